// Round 1
// baseline (121.367 us; speedup 1.0000x reference)
//
#include <hip/hip_runtime.h>

#define BLOCK 256
#define NBLOCKS 2048
#define BLOCK2 256

// Clang vector types so __builtin_nontemporal_load works on 16B/8B chunks.
typedef float v4f __attribute__((ext_vector_type(4)));
typedef int   v2i __attribute__((ext_vector_type(2)));

// One float4 = logits of 2 samples; one int2 = their targets.
// -log softmax at target t for C=2:  softplus( (x_other - x_t) )
//   t==1: lse - x1 = log(1+exp(x0-x1)) = softplus(x0-x1)
//   t==0: lse - x0 = log(1+exp(x1-x0)) = softplus(x1-x0)
// softplus(z) = max(z,0) + log(1+exp(-|z|))   (stable, 1 exp + 1 log)
__device__ __forceinline__ void acc_pair(v4f xv, v2i tv,
                                         float& s0, float& s1, unsigned int& c1)
{
    {
        float z = tv[0] ? (xv[0] - xv[1]) : (xv[1] - xv[0]);
        float l = fmaxf(z, 0.f) + __logf(1.f + __expf(-fabsf(z)));
        s1 += tv[0] ? l : 0.f;
        s0 += tv[0] ? 0.f : l;
        c1 += (tv[0] != 0);
    }
    {
        float z = tv[1] ? (xv[2] - xv[3]) : (xv[3] - xv[2]);
        float l = fmaxf(z, 0.f) + __logf(1.f + __expf(-fabsf(z)));
        s1 += tv[1] ? l : 0.f;
        s0 += tv[1] ? 0.f : l;
        c1 += (tv[1] != 0);
    }
}

// Stage 1: grid-stride over PAIRS of samples (float4 + int2 per lane — both
// fully lane-contiguous). Per-block partial sums to distinct workspace slots,
// no atomics; the kernel boundary provides cross-block ordering.
__global__ __launch_bounds__(BLOCK) void nll_partial(
    const v4f* __restrict__ xp,
    const v2i* __restrict__ tp,
    float* __restrict__ ps0,          // [NBLOCKS] sum(-logp | class0)
    float* __restrict__ ps1,          // [NBLOCKS] sum(-logp | class1)
    unsigned int* __restrict__ pc1,   // [NBLOCKS] count(class1)
    int npairs)
{
    int idx = blockIdx.x * BLOCK + threadIdx.x;
    int stride = gridDim.x * BLOCK;

    float s0 = 0.f, s1 = 0.f;
    unsigned int c1 = 0;

    int i = idx;
    // Main loop: 4 pairs per iteration, all 8 loads issued before any compute
    // (96 B in flight per thread for latency hiding). Streaming data (>L2),
    // so nontemporal.
    for (; i + 3 * stride < npairs; i += 4 * stride) {
        v4f x0 = __builtin_nontemporal_load(&xp[i]);
        v4f x1 = __builtin_nontemporal_load(&xp[i + stride]);
        v4f x2 = __builtin_nontemporal_load(&xp[i + 2 * stride]);
        v4f x3 = __builtin_nontemporal_load(&xp[i + 3 * stride]);
        v2i t0 = __builtin_nontemporal_load(&tp[i]);
        v2i t1 = __builtin_nontemporal_load(&tp[i + stride]);
        v2i t2 = __builtin_nontemporal_load(&tp[i + 2 * stride]);
        v2i t3 = __builtin_nontemporal_load(&tp[i + 3 * stride]);
        acc_pair(x0, t0, s0, s1, c1);
        acc_pair(x1, t1, s0, s1, c1);
        acc_pair(x2, t2, s0, s1, c1);
        acc_pair(x3, t3, s0, s1, c1);
    }
    for (; i < npairs; i += stride) {
        v4f xv = __builtin_nontemporal_load(&xp[i]);
        v2i tv = __builtin_nontemporal_load(&tp[i]);
        acc_pair(xv, tv, s0, s1, c1);
    }

    // wave64 reduce
    for (int off = 32; off > 0; off >>= 1) {
        s0 += __shfl_down(s0, off, 64);
        s1 += __shfl_down(s1, off, 64);
        c1 += __shfl_down(c1, off, 64);
    }

    __shared__ float sh0[BLOCK / 64];
    __shared__ float sh1[BLOCK / 64];
    __shared__ unsigned int shc[BLOCK / 64];

    int lane = threadIdx.x & 63;
    int wave = threadIdx.x >> 6;
    if (lane == 0) { sh0[wave] = s0; sh1[wave] = s1; shc[wave] = c1; }
    __syncthreads();

    if (threadIdx.x == 0) {
        float t0 = 0.f, t1 = 0.f;
        unsigned int tc = 0;
        for (int w = 0; w < BLOCK / 64; ++w) { t0 += sh0[w]; t1 += sh1[w]; tc += shc[w]; }
        ps0[blockIdx.x] = t0;   // plain store, unique address per block
        ps1[blockIdx.x] = t1;
        pc1[blockIdx.x] = tc;
    }
}

// Stage 2: one block reduces all partials, handles the (normally empty) tail,
// and writes the final scalar.
__global__ __launch_bounds__(BLOCK2) void nll_finalize(
    const float* __restrict__ ps0,
    const float* __restrict__ ps1,
    const unsigned int* __restrict__ pc1,
    const float* __restrict__ x,
    const int* __restrict__ tg,
    float* __restrict__ out,
    int P, int N, int tail_start)
{
    float s0 = 0.f, s1 = 0.f;
    unsigned int c1 = 0;
    for (int i = threadIdx.x; i < P; i += BLOCK2) {
        s0 += ps0[i];
        s1 += ps1[i];
        c1 += pc1[i];
    }

    for (int off = 32; off > 0; off >>= 1) {
        s0 += __shfl_down(s0, off, 64);
        s1 += __shfl_down(s1, off, 64);
        c1 += __shfl_down(c1, off, 64);
    }

    __shared__ float sh0[BLOCK2 / 64];
    __shared__ float sh1[BLOCK2 / 64];
    __shared__ unsigned int shc[BLOCK2 / 64];

    int lane = threadIdx.x & 63;
    int wave = threadIdx.x >> 6;
    if (lane == 0) { sh0[wave] = s0; sh1[wave] = s1; shc[wave] = c1; }
    __syncthreads();

    if (threadIdx.x == 0) {
        float t0 = 0.f, t1 = 0.f;
        unsigned int tc = 0;
        for (int w = 0; w < BLOCK2 / 64; ++w) { t0 += sh0[w]; t1 += sh1[w]; tc += shc[w]; }
        // tail samples (N % 2) — normally zero iterations
        for (int i = tail_start; i < N; ++i) {
            float a = x[2 * i], b = x[2 * i + 1];
            float z = tg[i] ? (a - b) : (b - a);
            float l = fmaxf(z, 0.f) + __logf(1.f + __expf(-fabsf(z)));
            if (tg[i]) { t1 += l; tc++; } else { t0 += l; }
        }
        unsigned int c0 = (unsigned int)N - tc;
        float r = (tc > 0) ? t1 / (float)tc : 0.f;
        float p = (c0 > 0) ? t0 / (float)c0 : 0.f;
        out[0] = p + r;
    }
}

// Fallback (tiny ws): atomic design, only used if ws_size < partial arrays.
__global__ void nll_atomic(const v4f* __restrict__ xp,
                           const v2i* __restrict__ tp,
                           float* __restrict__ wsf,
                           unsigned int* __restrict__ wsi,
                           int npairs)
{
    int idx = blockIdx.x * blockDim.x + threadIdx.x;
    int stride = gridDim.x * blockDim.x;
    float s0 = 0.f, s1 = 0.f;
    unsigned int c1 = 0;
    for (int i = idx; i < npairs; i += stride) {
        v4f xv = xp[i];
        v2i tv = tp[i];
        acc_pair(xv, tv, s0, s1, c1);
    }
    for (int off = 32; off > 0; off >>= 1) {
        s0 += __shfl_down(s0, off, 64);
        s1 += __shfl_down(s1, off, 64);
        c1 += __shfl_down(c1, off, 64);
    }
    __shared__ float sh0[4]; __shared__ float sh1[4]; __shared__ unsigned int shc[4];
    int lane = threadIdx.x & 63; int wave = threadIdx.x >> 6;
    if (lane == 0) { sh0[wave] = s0; sh1[wave] = s1; shc[wave] = c1; }
    __syncthreads();
    if (threadIdx.x == 0) {
        float t0 = 0.f, t1 = 0.f; unsigned int tc = 0;
        for (int w = 0; w < 4; ++w) { t0 += sh0[w]; t1 += sh1[w]; tc += shc[w]; }
        atomicAdd(&wsf[0], t0); atomicAdd(&wsf[1], t1); atomicAdd(&wsi[0], tc);
    }
}

__global__ void nll_atomic_fin(const float* __restrict__ x,
                               const int* __restrict__ tg,
                               const float* __restrict__ wsf,
                               const unsigned int* __restrict__ wsi,
                               float* __restrict__ out,
                               int N, int tail_start)
{
    float s0 = wsf[0], s1 = wsf[1];
    unsigned int c1 = wsi[0];
    for (int i = tail_start; i < N; ++i) {
        float a = x[2 * i], b = x[2 * i + 1];
        float z = tg[i] ? (a - b) : (b - a);
        float l = fmaxf(z, 0.f) + __logf(1.f + __expf(-fabsf(z)));
        if (tg[i]) { s1 += l; c1++; } else { s0 += l; }
    }
    unsigned int c0 = (unsigned int)N - c1;
    float r = (c1 > 0) ? s1 / (float)c1 : 0.f;
    float p = (c0 > 0) ? s0 / (float)c0 : 0.f;
    out[0] = p + r;
}

extern "C" void kernel_launch(void* const* d_in, const int* in_sizes, int n_in,
                              void* d_out, int out_size, void* d_ws, size_t ws_size,
                              hipStream_t stream) {
    const float* x = (const float*)d_in[0];
    const int* tg = (const int*)d_in[1];
    int N = in_sizes[1];
    float* out = (float*)d_out;

    int npairs = N / 2;
    int tail_start = npairs * 2;

    size_t need = (size_t)NBLOCKS * (4 + 4 + 4);  // ps0, ps1, pc1
    if (ws_size >= need) {
        float* ps0 = (float*)d_ws;
        float* ps1 = ps0 + NBLOCKS;
        unsigned int* pc1 = (unsigned int*)(ps1 + NBLOCKS);

        nll_partial<<<NBLOCKS, BLOCK, 0, stream>>>(
            (const v4f*)x, (const v2i*)tg, ps0, ps1, pc1, npairs);
        nll_finalize<<<1, BLOCK2, 0, stream>>>(
            ps0, ps1, pc1, x, tg, out, NBLOCKS, N, tail_start);
    } else {
        float* wsf = (float*)d_ws;
        unsigned int* wsi = (unsigned int*)((char*)d_ws + 8);
        hipMemsetAsync(d_ws, 0, 16, stream);
        nll_atomic<<<256, BLOCK, 0, stream>>>(
            (const v4f*)x, (const v2i*)tg, wsf, wsi, npairs);
        nll_atomic_fin<<<1, 1, 0, stream>>>(x, tg, wsf, wsi, out, N, tail_start);
    }
}

// Round 2
// 113.948 us; speedup vs baseline: 1.0651x; 1.0651x over previous
//
#include <hip/hip_runtime.h>

#define BLOCK 256
#define NBLOCKS 2048
#define BLOCK2 256

// -log softmax at target t for C=2:  softplus(x_other - x_t)
//   softplus(z) = max(z,0) + log(1+exp(-|z|))   (stable, 1 exp + 1 log)
__device__ __forceinline__ void acc_quad(float4 xa, float4 xb, int4 t,
                                         float& s0, float& s1, unsigned int& c1)
{
    {
        float z = t.x ? (xa.x - xa.y) : (xa.y - xa.x);
        float l = fmaxf(z, 0.f) + __logf(1.f + __expf(-fabsf(z)));
        s1 += t.x ? l : 0.f;
        s0 += t.x ? 0.f : l;
        c1 += (t.x != 0);
    }
    {
        float z = t.y ? (xa.z - xa.w) : (xa.w - xa.z);
        float l = fmaxf(z, 0.f) + __logf(1.f + __expf(-fabsf(z)));
        s1 += t.y ? l : 0.f;
        s0 += t.y ? 0.f : l;
        c1 += (t.y != 0);
    }
    {
        float z = t.z ? (xb.x - xb.y) : (xb.y - xb.x);
        float l = fmaxf(z, 0.f) + __logf(1.f + __expf(-fabsf(z)));
        s1 += t.z ? l : 0.f;
        s0 += t.z ? 0.f : l;
        c1 += (t.z != 0);
    }
    {
        float z = t.w ? (xb.z - xb.w) : (xb.w - xb.z);
        float l = fmaxf(z, 0.f) + __logf(1.f + __expf(-fabsf(z)));
        s1 += t.w ? l : 0.f;
        s0 += t.w ? 0.f : l;
        c1 += (t.w != 0);
    }
}

// Stage 1: grid-stride over quads of samples. All loads 16B lane-contiguous
// (measured-best layout: 2x float4 logits + 1x int4 targets per quad).
// Per-block partial sums to distinct workspace slots, no atomics; the kernel
// boundary provides cross-block ordering.
__global__ __launch_bounds__(BLOCK) void nll_partial(
    const float4* __restrict__ x4,
    const int4* __restrict__ t4,
    float* __restrict__ ps0,          // [NBLOCKS] sum(-logp | class0)
    float* __restrict__ ps1,          // [NBLOCKS] sum(-logp | class1)
    unsigned int* __restrict__ pc1,   // [NBLOCKS] count(class1)
    int nquads)
{
    int idx = blockIdx.x * BLOCK + threadIdx.x;
    int stride = gridDim.x * BLOCK;

    float s0 = 0.f, s1 = 0.f;
    unsigned int c1 = 0;

    int i = idx;
    // Unroll x2: issue all 6 loads (96 B/thread) before any compute.
    for (; i + stride < nquads; i += 2 * stride) {
        int j = i + stride;
        float4 xa0 = x4[2 * i];
        float4 xb0 = x4[2 * i + 1];
        float4 xa1 = x4[2 * j];
        float4 xb1 = x4[2 * j + 1];
        int4   t0  = t4[i];
        int4   t1  = t4[j];
        acc_quad(xa0, xb0, t0, s0, s1, c1);
        acc_quad(xa1, xb1, t1, s0, s1, c1);
    }
    for (; i < nquads; i += stride) {
        float4 xa = x4[2 * i];
        float4 xb = x4[2 * i + 1];
        int4   t  = t4[i];
        acc_quad(xa, xb, t, s0, s1, c1);
    }

    // wave64 reduce
    for (int off = 32; off > 0; off >>= 1) {
        s0 += __shfl_down(s0, off, 64);
        s1 += __shfl_down(s1, off, 64);
        c1 += __shfl_down(c1, off, 64);
    }

    __shared__ float sh0[BLOCK / 64];
    __shared__ float sh1[BLOCK / 64];
    __shared__ unsigned int shc[BLOCK / 64];

    int lane = threadIdx.x & 63;
    int wave = threadIdx.x >> 6;
    if (lane == 0) { sh0[wave] = s0; sh1[wave] = s1; shc[wave] = c1; }
    __syncthreads();

    if (threadIdx.x == 0) {
        float t0 = 0.f, t1 = 0.f;
        unsigned int tc = 0;
        for (int w = 0; w < BLOCK / 64; ++w) { t0 += sh0[w]; t1 += sh1[w]; tc += shc[w]; }
        ps0[blockIdx.x] = t0;   // plain store, unique address per block
        ps1[blockIdx.x] = t1;
        pc1[blockIdx.x] = tc;
    }
}

// Stage 2: one block reduces all partials, handles the (normally empty) tail,
// and writes the final scalar.
__global__ __launch_bounds__(BLOCK2) void nll_finalize(
    const float* __restrict__ ps0,
    const float* __restrict__ ps1,
    const unsigned int* __restrict__ pc1,
    const float* __restrict__ x,
    const int* __restrict__ tg,
    float* __restrict__ out,
    int P, int N, int tail_start)
{
    float s0 = 0.f, s1 = 0.f;
    unsigned int c1 = 0;
    for (int i = threadIdx.x; i < P; i += BLOCK2) {
        s0 += ps0[i];
        s1 += ps1[i];
        c1 += pc1[i];
    }

    for (int off = 32; off > 0; off >>= 1) {
        s0 += __shfl_down(s0, off, 64);
        s1 += __shfl_down(s1, off, 64);
        c1 += __shfl_down(c1, off, 64);
    }

    __shared__ float sh0[BLOCK2 / 64];
    __shared__ float sh1[BLOCK2 / 64];
    __shared__ unsigned int shc[BLOCK2 / 64];

    int lane = threadIdx.x & 63;
    int wave = threadIdx.x >> 6;
    if (lane == 0) { sh0[wave] = s0; sh1[wave] = s1; shc[wave] = c1; }
    __syncthreads();

    if (threadIdx.x == 0) {
        float t0 = 0.f, t1 = 0.f;
        unsigned int tc = 0;
        for (int w = 0; w < BLOCK2 / 64; ++w) { t0 += sh0[w]; t1 += sh1[w]; tc += shc[w]; }
        // tail samples (N % 4) — normally zero iterations
        for (int i = tail_start; i < N; ++i) {
            float a = x[2 * i], b = x[2 * i + 1];
            float z = tg[i] ? (a - b) : (b - a);
            float l = fmaxf(z, 0.f) + __logf(1.f + __expf(-fabsf(z)));
            if (tg[i]) { t1 += l; tc++; } else { t0 += l; }
        }
        unsigned int c0 = (unsigned int)N - tc;
        float r = (tc > 0) ? t1 / (float)tc : 0.f;
        float p = (c0 > 0) ? t0 / (float)c0 : 0.f;
        out[0] = p + r;
    }
}

// Fallback (tiny ws): atomic design, only used if ws_size < partial arrays.
__global__ void nll_atomic(const float4* __restrict__ x4,
                           const int4* __restrict__ t4,
                           float* __restrict__ wsf,
                           unsigned int* __restrict__ wsi,
                           int nquads)
{
    int idx = blockIdx.x * blockDim.x + threadIdx.x;
    int stride = gridDim.x * blockDim.x;
    float s0 = 0.f, s1 = 0.f;
    unsigned int c1 = 0;
    for (int i = idx; i < nquads; i += stride) {
        float4 xa = x4[2 * i];
        float4 xb = x4[2 * i + 1];
        int4   t  = t4[i];
        acc_quad(xa, xb, t, s0, s1, c1);
    }
    for (int off = 32; off > 0; off >>= 1) {
        s0 += __shfl_down(s0, off, 64);
        s1 += __shfl_down(s1, off, 64);
        c1 += __shfl_down(c1, off, 64);
    }
    __shared__ float sh0[4]; __shared__ float sh1[4]; __shared__ unsigned int shc[4];
    int lane = threadIdx.x & 63; int wave = threadIdx.x >> 6;
    if (lane == 0) { sh0[wave] = s0; sh1[wave] = s1; shc[wave] = c1; }
    __syncthreads();
    if (threadIdx.x == 0) {
        float t0 = 0.f, t1 = 0.f; unsigned int tc = 0;
        for (int w = 0; w < 4; ++w) { t0 += sh0[w]; t1 += sh1[w]; tc += shc[w]; }
        atomicAdd(&wsf[0], t0); atomicAdd(&wsf[1], t1); atomicAdd(&wsi[0], tc);
    }
}

__global__ void nll_atomic_fin(const float* __restrict__ x,
                               const int* __restrict__ tg,
                               const float* __restrict__ wsf,
                               const unsigned int* __restrict__ wsi,
                               float* __restrict__ out,
                               int N, int tail_start)
{
    float s0 = wsf[0], s1 = wsf[1];
    unsigned int c1 = wsi[0];
    for (int i = tail_start; i < N; ++i) {
        float a = x[2 * i], b = x[2 * i + 1];
        float z = tg[i] ? (a - b) : (b - a);
        float l = fmaxf(z, 0.f) + __logf(1.f + __expf(-fabsf(z)));
        if (tg[i]) { s1 += l; c1++; } else { s0 += l; }
    }
    unsigned int c0 = (unsigned int)N - c1;
    float r = (c1 > 0) ? s1 / (float)c1 : 0.f;
    float p = (c0 > 0) ? s0 / (float)c0 : 0.f;
    out[0] = p + r;
}

extern "C" void kernel_launch(void* const* d_in, const int* in_sizes, int n_in,
                              void* d_out, int out_size, void* d_ws, size_t ws_size,
                              hipStream_t stream) {
    const float* x = (const float*)d_in[0];
    const int* tg = (const int*)d_in[1];
    int N = in_sizes[1];
    float* out = (float*)d_out;

    int nquads = N / 4;
    int tail_start = nquads * 4;

    size_t need = (size_t)NBLOCKS * (4 + 4 + 4);  // ps0, ps1, pc1
    if (ws_size >= need) {
        float* ps0 = (float*)d_ws;
        float* ps1 = ps0 + NBLOCKS;
        unsigned int* pc1 = (unsigned int*)(ps1 + NBLOCKS);

        nll_partial<<<NBLOCKS, BLOCK, 0, stream>>>(
            (const float4*)x, (const int4*)tg, ps0, ps1, pc1, nquads);
        nll_finalize<<<1, BLOCK2, 0, stream>>>(
            ps0, ps1, pc1, x, tg, out, NBLOCKS, N, tail_start);
    } else {
        float* wsf = (float*)d_ws;
        unsigned int* wsi = (unsigned int*)((char*)d_ws + 8);
        hipMemsetAsync(d_ws, 0, 16, stream);
        nll_atomic<<<256, BLOCK, 0, stream>>>(
            (const float4*)x, (const int4*)tg, wsf, wsi, nquads);
        nll_atomic_fin<<<1, 1, 0, stream>>>(x, tg, wsf, wsi, out, N, tail_start);
    }
}